// Round 4
// baseline (62.891 us; speedup 1.0000x reference)
//
#include <hip/hip_runtime.h>

// PatchConsistencyLoss: structure [32,32,32,32] int32, patch 4x4x4 (64 voxels
// = one wave). Per-patch token histogram via 12-ballot bitwise match-mask
// (VOCAB=3717 < 4096): lanes with equal tokens end up with identical 64-bit
// masks; the first non-air lane of each mask is the representative and
// contributes -p*log(p+1e-10), p = count/tot(non-air). Air = {102,576,3352}.
// Fused single kernel: 256 blocks x 1024 threads (1 block/CU, 4 waves/SIMD),
// 4 patches/wave, block LDS reduce, one atomicAdd per block with the
// 1/(16384+1e-6) scale folded in. d_out zeroed by a tiny memset node.

__global__ __launch_bounds__(1024) void pcl_fused(const int* __restrict__ s,
                                                  float* __restrict__ out) {
    const int lane = threadIdx.x & 63;
    const int wave = threadIdx.x >> 6;
    const int wid = (blockIdx.x << 4) + wave;   // 0..4095, 4 patches each

    // lane -> (ld, lh, lw) within the 4x4x4 patch
    const int ld = lane >> 4;
    const int lh = (lane >> 2) & 3;
    const int lw = lane & 3;

    float e = 0.0f;
#pragma unroll
    for (int it = 0; it < 4; ++it) {
        const int patch = (wid << 2) + it;      // 0..16383
        // patch = ((b*8 + pd)*8 + ph)*8 + pw
        const int b  = patch >> 9;
        const int pd = (patch >> 6) & 7;
        const int ph = (patch >> 3) & 7;
        const int pw = patch & 7;
        const int idx = ((b * 32 + (pd << 2) + ld) * 32 + (ph << 2) + lh) * 32
                        + (pw << 2) + lw;

        const int tok = s[idx];
        const bool air = (tok == 102) || (tok == 576) || (tok == 3352);
        const int tot = __popcll(__ballot(!air));

        // bitwise match-mask: lanes holding my exact token value
        unsigned long long m = ~0ull;
#pragma unroll
        for (int bit = 0; bit < 12; ++bit) {
            const unsigned long long bal = __ballot((tok >> bit) & 1);
            m &= ((tok >> bit) & 1) ? bal : ~bal;
        }

        const int first = __ffsll((unsigned long long)m) - 1;
        if (!air && first == lane) {            // one representative per token
            const float p = (float)__popcll(m) / (float)tot;  // tot >= 1 here
            e -= p * __logf(p + 1e-10f);
        }
    }

    // wave reduction
#pragma unroll
    for (int off = 32; off > 0; off >>= 1) e += __shfl_xor(e, off, 64);

    __shared__ float ws16[16];
    if (lane == 0) ws16[wave] = e;
    __syncthreads();

    if (wave == 0) {
        float t = (lane < 16) ? ws16[lane] : 0.0f;
#pragma unroll
        for (int off = 8; off > 0; off >>= 1) t += __shfl_xor(t, off, 64);
        if (lane == 0)
            atomicAdd(out, t * (1.0f / (16384.0f + 1e-6f)));
    }
}

extern "C" void kernel_launch(void* const* d_in, const int* in_sizes, int n_in,
                              void* d_out, int out_size, void* d_ws, size_t ws_size,
                              hipStream_t stream) {
    const int* s = (const int*)d_in[0];
    float* out = (float*)d_out;

    // d_out is re-poisoned to 0xAA before every timed launch; we accumulate
    // into it, so zero it first (memset node is graph-capturable).
    hipMemsetAsync(out, 0, sizeof(float), stream);
    pcl_fused<<<256, 1024, 0, stream>>>(s, out);
}

// Round 5
// 59.101 us; speedup vs baseline: 1.0641x; 1.0641x over previous
//
#include <hip/hip_runtime.h>

// PatchConsistencyLoss: structure [32,32,32,32] int32, patch 4x4x4 (64 voxels
// = one wave). Per-patch token histogram via 12-ballot bitwise match-mask
// (VOCAB=3717 < 4096): lanes with equal tokens end up with identical 64-bit
// masks; the first non-air lane of each mask is the representative and
// contributes -p*log(p+1e-10), p = count/tot(non-air). Air = {102,576,3352}.
// Two kernels (measured faster than fused+memset+atomics, R2=59.8 vs R4=62.9):
//   k1: 1024 blocks x 256, 4 patches/wave, writes 1024 block partials to ws.
//   k2: one 64-lane wave, float4 loads, shuffle reduce, applies scale.

__global__ __launch_bounds__(256) void pcl_k1(const int* __restrict__ s,
                                              float* __restrict__ partial) {
    const int lane = threadIdx.x & 63;
    const int wave = threadIdx.x >> 6;
    const int wid = (blockIdx.x << 2) + wave;   // 0..4095, 4 patches each

    // lane -> (ld, lh, lw) within the 4x4x4 patch
    const int ld = lane >> 4;
    const int lh = (lane >> 2) & 3;
    const int lw = lane & 3;

    float e = 0.0f;
#pragma unroll
    for (int it = 0; it < 4; ++it) {
        const int patch = (wid << 2) + it;      // 0..16383
        // patch = ((b*8 + pd)*8 + ph)*8 + pw
        const int b  = patch >> 9;
        const int pd = (patch >> 6) & 7;
        const int ph = (patch >> 3) & 7;
        const int pw = patch & 7;
        const int idx = ((b * 32 + (pd << 2) + ld) * 32 + (ph << 2) + lh) * 32
                        + (pw << 2) + lw;

        const int tok = s[idx];
        const bool air = (tok == 102) || (tok == 576) || (tok == 3352);
        const int tot = __popcll(__ballot(!air));

        // bitwise match-mask: lanes holding my exact token value
        unsigned long long m = ~0ull;
#pragma unroll
        for (int bit = 0; bit < 12; ++bit) {
            const unsigned long long bal = __ballot((tok >> bit) & 1);
            m &= ((tok >> bit) & 1) ? bal : ~bal;
        }

        const int first = __ffsll((unsigned long long)m) - 1;
        if (!air && first == lane) {            // one representative per token
            const float p = (float)__popcll(m) / (float)tot;  // tot >= 1 here
            e -= p * __logf(p + 1e-10f);
        }
    }

    // wave reduction
#pragma unroll
    for (int off = 32; off > 0; off >>= 1) e += __shfl_xor(e, off, 64);

    __shared__ float ws4[4];
    if (lane == 0) ws4[wave] = e;
    __syncthreads();
    if (threadIdx.x == 0)
        partial[blockIdx.x] = ws4[0] + ws4[1] + ws4[2] + ws4[3];
}

// Single 64-lane wave: 1024 floats = 16 float4 per... (1024/4=256 float4,
// 4 per lane). Shuffle reduce, scale, write.
__global__ __launch_bounds__(64) void pcl_k2(const float* __restrict__ partial,
                                             float* __restrict__ out) {
    const float4* p4 = (const float4*)partial;
    float sum = 0.0f;
#pragma unroll
    for (int i = 0; i < 4; ++i) {
        const float4 v = p4[threadIdx.x + (i << 6)];
        sum += v.x + v.y + v.z + v.w;
    }
#pragma unroll
    for (int off = 32; off > 0; off >>= 1) sum += __shfl_xor(sum, off, 64);
    if (threadIdx.x == 0)
        out[0] = sum * (1.0f / (16384.0f + 1e-6f));
}

extern "C" void kernel_launch(void* const* d_in, const int* in_sizes, int n_in,
                              void* d_out, int out_size, void* d_ws, size_t ws_size,
                              hipStream_t stream) {
    const int* s = (const int*)d_in[0];
    float* out = (float*)d_out;
    float* partial = (float*)d_ws;   // 1024 floats = 4 KB scratch

    pcl_k1<<<1024, 256, 0, stream>>>(s, partial);
    pcl_k2<<<1, 64, 0, stream>>>(partial, out);
}